// Round 1
// baseline (188.962 us; speedup 1.0000x reference)
//
#include <hip/hip_runtime.h>

// binary_decoder: bit-exact float32 emulation of the reference's sequential
// carry-save adder.
//
// Shapes: x[8][2048], weight[2048][4096] (4096 = 512 outputs * 8 bit-lanes).
// 4096 independent chains (b, o); each chain has 8 float "bit lanes" coupled
// only by a carry that moves one lane toward MSB with a one-step delay.
//
// Exactness argument (must match numpy float32 sequential semantics):
//   a  = x * hard, hard in {0,1}  -> exact, == (w>=0.5 ? x : 0)
//   u  = fp32(s + a)              -> same single rounding as reference
//   t  = fp32(u + c)              -> same association (s + a) + c
//   half = floor(t*0.5); t < 4 always => half = (t>=2) ? 1 : 0
//   s' = t - 2*half: exact both branches (t-2 exact for t in [2,4))
//   c'_j = half_{j-1}, c'_0 = 0   -> DPP row_shr:1 + mask lanes (lane&7)==0
//
// Mapping: 64-thread block = 1 wave = 8 chains (same b, o = og*8+g).
// lane = g*8 + j; weight index k = og*64 + lane -> fully coalesced loads.
// x[b][f] is wave-uniform (b per block) -> scalar loads.
// Grid (8,8,8): og = bx + 8*by, b = bz; linear%8 = bx so the 8 b-duplicates
// of an o-group land on the same XCD (L2 reuse of weight lines).

#define F_DIM 2048
#define K_DIM 4096
#define B_DIM 8
#define UNROLL 16

__device__ __forceinline__ float dpp_row_shr1(float v) {
    // row_shr:1 (0x111), all rows/banks, bound_ctrl: out-of-row source -> 0
    int r = __builtin_amdgcn_update_dpp(0, __float_as_int(v), 0x111, 0xf, 0xf, true);
    return __int_as_float(r);
}

__global__ __launch_bounds__(64) void csa_kernel(const float* __restrict__ x,
                                                 const float* __restrict__ weight,
                                                 float* __restrict__ out) {
    const int lane = threadIdx.x;                 // 0..63
    const int og   = blockIdx.x + 8 * blockIdx.y; // 0..63
    const int b    = blockIdx.z;                  // 0..7
    const int k    = og * 64 + lane;              // 0..4095 column index
    const bool p0  = ((lane & 7) == 0);           // bit-lane 0 of each chain

    const float* wp = weight + k;                 // stride K_DIM per f
    const float* xp = x + b * F_DIM;              // wave-uniform row

    float s = 0.0f, c = 0.0f;

    float wbuf[UNROLL];
    float xbuf[UNROLL];
#pragma unroll
    for (int u = 0; u < UNROLL; ++u) {
        wbuf[u] = wp[u * K_DIM];
        xbuf[u] = xp[u];
    }

    for (int f0 = 0; f0 < F_DIM; f0 += UNROLL) {
        // prefetch next block (clamped at the tail; harmless re-reads)
        float wn[UNROLL];
        float xn[UNROLL];
#pragma unroll
        for (int u = 0; u < UNROLL; ++u) {
            int fn = f0 + UNROLL + u;
            fn = (fn < F_DIM) ? fn : (F_DIM - 1);
            wn[u] = wp[fn * K_DIM];
            xn[u] = xp[fn];
        }
#pragma unroll
        for (int u = 0; u < UNROLL; ++u) {
            // a is off the critical path (w, x prefetched)
            float a  = (wbuf[u] >= 0.5f) ? xbuf[u] : 0.0f;
            float uu = s + a;        // fp32(s + a)
            float t  = uu + c;       // fp32((s+a) + c)
            bool  ge = (t >= 2.0f);
            float h  = ge ? 1.0f : 0.0f;       // == floor(t*0.5), t < 4
            s = ge ? (t - 2.0f) : t;           // == t - 2*half, exact
            float hs = dpp_row_shr1(h);        // carry toward MSB lane
            c = p0 ? 0.0f : hs;                // chain-boundary carry-in = 0
        }
#pragma unroll
        for (int u = 0; u < UNROLL; ++u) {
            wbuf[u] = wn[u];
            xbuf[u] = xn[u];
        }
    }

    // outputs: s then carry, both [B][O][8] flat = [b][k]
    out[b * K_DIM + k]                  = s;
    out[B_DIM * K_DIM + b * K_DIM + k]  = c;
}

extern "C" void kernel_launch(void* const* d_in, const int* in_sizes, int n_in,
                              void* d_out, int out_size, void* d_ws, size_t ws_size,
                              hipStream_t stream) {
    (void)in_sizes; (void)n_in; (void)d_ws; (void)ws_size; (void)out_size;
    const float* x      = (const float*)d_in[0];
    const float* weight = (const float*)d_in[1];
    float* out          = (float*)d_out;

    dim3 grid(8, 8, 8);   // og = x + 8y (64 o-groups), b = z
    dim3 block(64);
    csa_kernel<<<grid, block, 0, stream>>>(x, weight, out);
}

// Round 2
// 155.637 us; speedup vs baseline: 1.2141x; 1.2141x over previous
//
#include <hip/hip_runtime.h>

// binary_decoder: bit-exact float32 emulation of the reference's sequential
// carry-save adder. See round-1 notes for the exactness argument (verified:
// absmax == 0.0).
//
// Round-2 changes:
//  - Prefetch distance 4 blocks of 16 (64 steps ~ 1100+ cyc of compute in
//    flight) via wb[4][16] circular register buffer. Round 1 had distance 1
//    (~300 cyc) -> ~600 cyc vmcnt(0) stall per 16 steps with only 0.5
//    waves/SIMD to hide HBM latency (~900 cyc).
//  - Carry path shortened: h = (t>=2) ? kmask : 0 with kmask precomputed as
//    0.0 on MSB lanes (lane&7==7), 1.0 elsewhere. DPP row_shr:1 then feeds c
//    directly (no post-DPP mask): lane&7==0 lanes receive either the zeroed
//    lane-7 h or bound_ctrl zero. Bit-identical to round 1, one fewer
//    dependent op on the c -> t' chain.

#define F_DIM 2048
#define K_DIM 4096
#define B_DIM 8
#define U     16   // steps per block
#define NB    4    // buffers: prefetch distance = (NB-1)*U = 48 steps min

__device__ __forceinline__ float dpp_row_shr1(float v) {
    // row_shr:1 (0x111), all rows/banks, bound_ctrl: out-of-row source -> 0
    int r = __builtin_amdgcn_update_dpp(0, __float_as_int(v), 0x111, 0xf, 0xf, true);
    return __int_as_float(r);
}

__global__ __launch_bounds__(64) void csa_kernel(const float* __restrict__ x,
                                                 const float* __restrict__ weight,
                                                 float* __restrict__ out) {
    const int lane = threadIdx.x;                 // 0..63
    const int og   = blockIdx.x + 8 * blockIdx.y; // 0..63
    const int b    = blockIdx.z;                  // 0..7
    const int k    = og * 64 + lane;              // 0..4095 column index

    // 1.0 everywhere except the MSB bit-lane of each chain (its carry-out
    // must not propagate into the next chain's LSB lane).
    const float kmask = ((lane & 7) == 7) ? 0.0f : 1.0f;

    const float* wp = weight + k;                 // stride K_DIM per f
    const float* xp = x + b * F_DIM;              // wave-uniform row (SGPR loads)

    float wb[NB][U];
    float xb[NB][U];

    // prologue: fill all NB buffers (f = 0 .. NB*U-1)
#pragma unroll
    for (int p = 0; p < NB; ++p) {
#pragma unroll
        for (int u = 0; u < U; ++u) {
            wb[p][u] = wp[(p * U + u) * K_DIM];
            xb[p][u] = xp[p * U + u];
        }
    }

    float s = 0.0f, c = 0.0f;

    for (int f0 = 0; f0 < F_DIM; f0 += NB * U) {   // 32 iterations
#pragma unroll
        for (int p = 0; p < NB; ++p) {
            // ---- compute block (f0 + p*U .. +U-1) from wb[p]/xb[p] ----
#pragma unroll
            for (int u = 0; u < U; ++u) {
                float a  = (wb[p][u] >= 0.5f) ? xb[p][u] : 0.0f; // off-path
                float uu = s + a;         // fp32(s + a)
                float t  = uu + c;        // fp32((s+a) + c)
                bool  ge = (t >= 2.0f);
                float h  = ge ? kmask : 0.0f;   // floor(t/2), pre-masked
                s = ge ? (t - 2.0f) : t;        // exact
                c = dpp_row_shr1(h);            // carry toward MSB lane
            }
            // ---- refill wb[p] for f0 + p*U + NB*U (consumed in 4 blocks) ----
            int fb = f0 + p * U + NB * U;
            if (fb < F_DIM) {                    // uniform branch
#pragma unroll
                for (int u = 0; u < U; ++u) {
                    wb[p][u] = wp[(fb + u) * K_DIM];
                    xb[p][u] = xp[fb + u];
                }
            }
        }
    }

    // outputs: s then carry, both [B][O*8] flat = [b][k]
    out[b * K_DIM + k]                 = s;
    out[B_DIM * K_DIM + b * K_DIM + k] = c;
}

extern "C" void kernel_launch(void* const* d_in, const int* in_sizes, int n_in,
                              void* d_out, int out_size, void* d_ws, size_t ws_size,
                              hipStream_t stream) {
    (void)in_sizes; (void)n_in; (void)d_ws; (void)ws_size; (void)out_size;
    const float* x      = (const float*)d_in[0];
    const float* weight = (const float*)d_in[1];
    float* out          = (float*)d_out;

    dim3 grid(8, 8, 8);   // og = x + 8y (64 o-groups), b = z (linear%8 = XCD)
    dim3 block(64);
    csa_kernel<<<grid, block, 0, stream>>>(x, weight, out);
}

// Round 3
// 127.248 us; speedup vs baseline: 1.4850x; 1.2231x over previous
//
#include <hip/hip_runtime.h>

// binary_decoder: bit-exact float32 emulation of the reference's sequential
// carry-save adder (absmax == 0.0 verified in rounds 1-2).
//
// Round-3 changes (diagnosis: VGPR_Count=44 in round 2 proves the scheduler
// collapsed the 4-deep prefetch buffer to minimize register pressure; x was
// scalarized to s_load whose out-of-order returns force lgkmcnt(0) drains):
//  - __launch_bounds__(64, 1): min-waves-per-EU = 1 -> VGPR budget ~512, so
//    the pressure heuristic lets wb[4][16]+xb[4][4] stay resident and the
//    refill loads stay hoisted ~48 steps ahead of use.
//  - x loaded through an opaque-zero VGPR offset (asm v_mov_b32 0) so the
//    address is not provably uniform -> global_load_dwordx4 (vmcnt domain,
//    fine-grained waits, broadcast from L1), 1 instr per 4 steps.
//  - Branch-free refill (clamped block base) -> straight-line unrolled body.
//
// Exactness (unchanged): a = (w>=0.5 ? x : 0) == x*hard exactly;
// uu = fp32(s+a); t = fp32(uu+c) matches reference association; t < 4 so
// floor(t/2) = (t>=2); s' = t-2 exact for t in [2,4). Carry shift via DPP
// row_shr:1 with h pre-masked to 0 on MSB lanes (lane&7==7) so chain
// boundaries never leak; bound_ctrl zeroes lanes 0/16/32/48.

#define F_DIM 2048
#define K_DIM 4096
#define B_DIM 8
#define U     16   // steps per block
#define NB    4    // buffers: prefetch distance (NB-1)*U = 48 steps

__device__ __forceinline__ float dpp_row_shr1(float v) {
    // row_shr:1 (0x111), all rows/banks, bound_ctrl: out-of-row source -> 0
    int r = __builtin_amdgcn_update_dpp(0, __float_as_int(v), 0x111, 0xf, 0xf, true);
    return __int_as_float(r);
}

__global__ __launch_bounds__(64, 1) void csa_kernel(const float* __restrict__ x,
                                                    const float* __restrict__ weight,
                                                    float* __restrict__ out) {
    const int lane = threadIdx.x;                 // 0..63
    const int og   = blockIdx.x + 8 * blockIdx.y; // 0..63
    const int b    = blockIdx.z;                  // 0..7
    const int k    = og * 64 + lane;              // 0..4095 column index

    // 1.0 everywhere except the MSB bit-lane of each chain.
    const float kmask = ((lane & 7) == 7) ? 0.0f : 1.0f;

    // Opaque zero in a VGPR: makes the x address divergent to the compiler,
    // forcing a vector load (vmcnt domain) instead of s_load (lgkmcnt,
    // out-of-order returns -> full drains on every use).
    int zero;
    asm volatile("v_mov_b32 %0, 0" : "=v"(zero));

    const float*  wp  = weight + k;                           // stride K_DIM
    const float4* xp4 = (const float4*)(x + b * F_DIM) + zero; // wave-"divergent"

    float  wb[NB][U];
    float4 xb[NB][U / 4];

    // prologue: fill all NB buffers (f = 0 .. NB*U-1)
#pragma unroll
    for (int p = 0; p < NB; ++p) {
#pragma unroll
        for (int u = 0; u < U; ++u)
            wb[p][u] = wp[(p * U + u) * K_DIM];
#pragma unroll
        for (int q = 0; q < U / 4; ++q)
            xb[p][q] = xp4[(p * U) / 4 + q];
    }

    float s = 0.0f, c = 0.0f;

    for (int f0 = 0; f0 < F_DIM; f0 += NB * U) {   // 32 iterations
#pragma unroll
        for (int p = 0; p < NB; ++p) {
            // ---- compute block from wb[p]/xb[p] ----
            const float* xf = (const float*)&xb[p][0];
#pragma unroll
            for (int u = 0; u < U; ++u) {
                float a  = (wb[p][u] >= 0.5f) ? xf[u] : 0.0f; // off-chain
                float uu = s + a;          // fp32(s + a)
                float t  = uu + c;         // fp32((s+a) + c)
                bool  ge = (t >= 2.0f);
                float h  = ge ? kmask : 0.0f;   // floor(t/2), pre-masked
                s = ge ? (t - 2.0f) : t;        // exact
                c = dpp_row_shr1(h);            // carry toward MSB lane
            }
            // ---- branch-free refill for use NB-1 blocks later ----
            int fb = f0 + p * U + NB * U;
            int fc = (fb <= F_DIM - U) ? fb : (F_DIM - U); // clamped re-read
#pragma unroll
            for (int u = 0; u < U; ++u)
                wb[p][u] = wp[(fc + u) * K_DIM];
#pragma unroll
            for (int q = 0; q < U / 4; ++q)
                xb[p][q] = xp4[fc / 4 + q];
        }
    }

    // outputs: s then carry, both [B][O*8] flat = [b][k]
    out[b * K_DIM + k]                 = s;
    out[B_DIM * K_DIM + b * K_DIM + k] = c;
}

extern "C" void kernel_launch(void* const* d_in, const int* in_sizes, int n_in,
                              void* d_out, int out_size, void* d_ws, size_t ws_size,
                              hipStream_t stream) {
    (void)in_sizes; (void)n_in; (void)d_ws; (void)ws_size; (void)out_size;
    const float* x      = (const float*)d_in[0];
    const float* weight = (const float*)d_in[1];
    float* out          = (float*)d_out;

    dim3 grid(8, 8, 8);   // og = x + 8y (64 o-groups), b = z (linear%8 = XCD)
    dim3 block(64);
    csa_kernel<<<grid, block, 0, stream>>>(x, weight, out);
}

// Round 4
// 124.398 us; speedup vs baseline: 1.5190x; 1.0229x over previous
//
#include <hip/hip_runtime.h>

// binary_decoder: bit-exact float32 emulation of the reference's sequential
// carry-save adder (absmax == 0.0 verified rounds 1-3).
//
// Round-4 changes (diagnosis: vmcnt queue is 6 bits = max 63 outstanding
// VMEM ops/wave; round 3's steady state issued up to ~68 -> load issue
// itself blocked, serializing with memory latency regardless of software
// prefetch depth):
//  - The chain only needs (w >= 0.5) -- ONE BIT per weight. Pass 1 packs
//    weight (32 MB) into a 1 MB bit array laid out so the main wave's load
//    of 1 dword covers 32 steps, fully coalesced: pk[og][f/32][lane].
//  - Main kernel: 1 bit-dword load / 32 steps + 1 float4 x-load / 4 steps
//    = 9 loads per 32-step group, 4-deep rotation -> <= ~30 outstanding.
//  - a recovered exactly: m = sext(bit) ; a = as_float(m & as_int(x)).
//    bit=1 -> a == x exactly; bit=0 -> +0.0f. Identical to x*hard (x >= 0).
//  - Fallback to the round-3 kernel if ws_size < 1 MB (host-side check,
//    deterministic every call).
//
// Exactness of the chain (unchanged): uu = fp32(s+a); t = fp32(uu+c) matches
// the reference association; t < 4 so floor(t/2) = (t>=2); s' = t-2 exact on
// [2,4). Carry via DPP row_shr:1, h pre-masked to 0 on MSB lanes.

#define F_DIM 2048
#define K_DIM 4096
#define B_DIM 8
#define G     32            // steps per group = bits per packed dword
#define NG    (F_DIM / G)   // 64 groups
#define NB2   4             // rotating buffer depth (prefetch distance 3 groups)

#define PK_BYTES (64 * NG * 64 * 4)  // 1 MB: [og][f32][lane] dwords

__device__ __forceinline__ float dpp_row_shr1(float v) {
    // row_shr:1 (0x111), all rows/banks, bound_ctrl: out-of-row source -> 0
    int r = __builtin_amdgcn_update_dpp(0, __float_as_int(v), 0x111, 0xf, 0xf, true);
    return __int_as_float(r);
}

__device__ __forceinline__ int sext_bit(unsigned bits, int u) {
#if __has_builtin(__builtin_amdgcn_sbfe)
    return __builtin_amdgcn_sbfe((int)bits, (unsigned)u, 1u);  // v_bfe_i32
#else
    return ((int)(bits << (31 - u))) >> 31;
#endif
}

// ---------------- pass 1: pack (w >= 0.5) bits -----------------------------
// pk[(og*64 + f32)*64 + lane] bit j = (w[(f32*32+j)][og*64+lane] >= 0.5)
__global__ __launch_bounds__(64) void pack_kernel(const float* __restrict__ w,
                                                  unsigned* __restrict__ pk) {
    const int lane = threadIdx.x;      // 0..63 -> column within og
    const int og   = blockIdx.x;       // 0..63
    const int f32  = blockIdx.y;       // 0..63
    const float* wp = w + og * 64 + lane;
    unsigned bits = 0;
#pragma unroll
    for (int j = 0; j < 32; ++j) {
        float wv = wp[(f32 * 32 + j) * K_DIM];   // coalesced 256B per j
        bits |= (wv >= 0.5f ? 1u : 0u) << j;
    }
    pk[(og * 64 + f32) * 64 + lane] = bits;
}

// ---------------- pass 2: the sequential chain -----------------------------
__global__ __launch_bounds__(64, 1) void csa_main(const float* __restrict__ x,
                                                  const unsigned* __restrict__ pk,
                                                  float* __restrict__ out) {
    const int lane = threadIdx.x;                 // 0..63
    const int og   = blockIdx.x + 8 * blockIdx.y; // 0..63
    const int b    = blockIdx.z;                  // 0..7
    const int k    = og * 64 + lane;

    // 1.0 everywhere except the MSB bit-lane of each chain.
    const float kmask = ((lane & 7) == 7) ? 0.0f : 1.0f;

    // Opaque zero: keep the x address out of the SMEM (lgkmcnt) domain.
    int zero;
    asm volatile("v_mov_b32 %0, 0" : "=v"(zero));

    const unsigned* bp  = pk + og * (NG * 64) + lane;           // +64 per group
    const float4*   xp4 = (const float4*)(x + b * F_DIM) + zero;

    unsigned bbuf[NB2];
    float4   xb[NB2][G / 4];

    // prologue: groups 0..NB2-1
#pragma unroll
    for (int p = 0; p < NB2; ++p) {
        bbuf[p] = bp[p * 64];
#pragma unroll
        for (int q = 0; q < G / 4; ++q)
            xb[p][q] = xp4[p * (G / 4) + q];
    }

    float s = 0.0f, c = 0.0f;

    for (int g0 = 0; g0 < NG; g0 += NB2) {   // 16 iterations
#pragma unroll
        for (int p = 0; p < NB2; ++p) {
            const float*   xf   = (const float*)&xb[p][0];
            const unsigned bits = bbuf[p];
#pragma unroll
            for (int u = 0; u < G; ++u) {
                int   m  = sext_bit(bits, u);                         // off-chain
                float a  = __int_as_float(m & __float_as_int(xf[u])); // == x*hard
                float uu = s + a;          // fp32(s + a)
                float t  = uu + c;         // fp32((s+a) + c)
                bool  ge = (t >= 2.0f);
                float h  = ge ? kmask : 0.0f;
                s = ge ? (t - 2.0f) : t;   // exact
                c = dpp_row_shr1(h);
            }
            // refill for use NB2-1 groups later (clamped tail re-read)
            int gb = g0 + p + NB2;
            int gc = (gb < NG) ? gb : (NG - 1);
            bbuf[p] = bp[gc * 64];
#pragma unroll
            for (int q = 0; q < G / 4; ++q)
                xb[p][q] = xp4[gc * (G / 4) + q];
        }
    }

    out[b * K_DIM + k]                 = s;
    out[B_DIM * K_DIM + b * K_DIM + k] = c;
}

// ---------------- fallback (round-3 kernel) if ws is too small -------------
#define U_FB  16
#define NB_FB 4
__global__ __launch_bounds__(64, 1) void csa_fallback(const float* __restrict__ x,
                                                      const float* __restrict__ weight,
                                                      float* __restrict__ out) {
    const int lane = threadIdx.x;
    const int og   = blockIdx.x + 8 * blockIdx.y;
    const int b    = blockIdx.z;
    const int k    = og * 64 + lane;
    const float kmask = ((lane & 7) == 7) ? 0.0f : 1.0f;
    int zero;
    asm volatile("v_mov_b32 %0, 0" : "=v"(zero));
    const float*  wp  = weight + k;
    const float4* xp4 = (const float4*)(x + b * F_DIM) + zero;
    float  wb[NB_FB][U_FB];
    float4 xb[NB_FB][U_FB / 4];
#pragma unroll
    for (int p = 0; p < NB_FB; ++p) {
#pragma unroll
        for (int u = 0; u < U_FB; ++u) wb[p][u] = wp[(p * U_FB + u) * K_DIM];
#pragma unroll
        for (int q = 0; q < U_FB / 4; ++q) xb[p][q] = xp4[(p * U_FB) / 4 + q];
    }
    float s = 0.0f, c = 0.0f;
    for (int f0 = 0; f0 < F_DIM; f0 += NB_FB * U_FB) {
#pragma unroll
        for (int p = 0; p < NB_FB; ++p) {
            const float* xf = (const float*)&xb[p][0];
#pragma unroll
            for (int u = 0; u < U_FB; ++u) {
                float a  = (wb[p][u] >= 0.5f) ? xf[u] : 0.0f;
                float uu = s + a;
                float t  = uu + c;
                bool  ge = (t >= 2.0f);
                float h  = ge ? kmask : 0.0f;
                s = ge ? (t - 2.0f) : t;
                c = dpp_row_shr1(h);
            }
            int fb = f0 + p * U_FB + NB_FB * U_FB;
            int fc = (fb <= F_DIM - U_FB) ? fb : (F_DIM - U_FB);
#pragma unroll
            for (int u = 0; u < U_FB; ++u) wb[p][u] = wp[(fc + u) * K_DIM];
#pragma unroll
            for (int q = 0; q < U_FB / 4; ++q) xb[p][q] = xp4[fc / 4 + q];
        }
    }
    out[b * K_DIM + k]                 = s;
    out[B_DIM * K_DIM + b * K_DIM + k] = c;
}

extern "C" void kernel_launch(void* const* d_in, const int* in_sizes, int n_in,
                              void* d_out, int out_size, void* d_ws, size_t ws_size,
                              hipStream_t stream) {
    (void)in_sizes; (void)n_in; (void)out_size;
    const float* x      = (const float*)d_in[0];
    const float* weight = (const float*)d_in[1];
    float* out          = (float*)d_out;

    if (ws_size >= (size_t)PK_BYTES && d_ws != nullptr) {
        unsigned* pk = (unsigned*)d_ws;
        pack_kernel<<<dim3(64, 64, 1), dim3(64), 0, stream>>>(weight, pk);
        csa_main<<<dim3(8, 8, 8), dim3(64), 0, stream>>>(x, pk, out);
    } else {
        csa_fallback<<<dim3(8, 8, 8), dim3(64), 0, stream>>>(x, weight, out);
    }
}